// Round 1
// baseline (355.229 us; speedup 1.0000x reference)
//
#include <hip/hip_runtime.h>

typedef unsigned short u16;
typedef __attribute__((ext_vector_type(8))) short short8;   // 8 x bf16 (4 VGPRs)
typedef __attribute__((ext_vector_type(4))) short short4v;
typedef __attribute__((ext_vector_type(4))) float f32x4;

#define B_  4
#define T_  2048
#define D_  1024
#define H_  16
#define HS_ 64
#define M_    (B_ * T_)        /* 8192 */
#define NQKV_ (H_ * 3 * HS_)   /* 3072 */

__device__ __forceinline__ u16 f2bf(float f) {
  union { float f; unsigned u; } v; v.f = f;
  unsigned u = v.u;
  return (u16)((u + 0x7FFFu + ((u >> 16) & 1u)) >> 16);  // RNE
}

// ---------------- convert x (fp32) -> bf16 ----------------
__global__ void k_cvt_x(const float* __restrict__ x, u16* __restrict__ o, int n4) {
  int i = blockIdx.x * 256 + threadIdx.x;
  if (i < n4) {
    float4 v = ((const float4*)x)[i];
    short4v d;
    d[0] = (short)f2bf(v.x); d[1] = (short)f2bf(v.y);
    d[2] = (short)f2bf(v.z); d[3] = (short)f2bf(v.w);
    ((short4v*)o)[i] = d;
  }
}

// ------- transpose+convert: in fp32 [R][C] (+h*sIn) -> out bf16 [C][R] (+h*sOut) -------
__global__ void k_transpose_cvt(const float* __restrict__ in, u16* __restrict__ out,
                                int R, int C, long sIn, long sOut) {
  __shared__ float tile[32][33];
  int h = blockIdx.z;
  const float* src = in + (long)h * sIn;
  u16* dst = out + (long)h * sOut;
  int r0 = blockIdx.y * 32, c0 = blockIdx.x * 32;
  int tx = threadIdx.x, ty = threadIdx.y;  // 32 x 8
  #pragma unroll
  for (int i = 0; i < 32; i += 8) {
    int r = r0 + ty + i, c = c0 + tx;
    tile[ty + i][tx] = (r < R && c < C) ? src[(long)r * C + c] : 0.f;
  }
  __syncthreads();
  #pragma unroll
  for (int i = 0; i < 32; i += 8) {
    int c = c0 + ty + i, r = r0 + tx;
    if (c < C && r < R) dst[(long)c * R + r] = f2bf(tile[tx][ty + i]);
  }
}

// ---------------- GEMM: C[M][N] = A[M][K] @ Bt[N][K]^T (bf16 in, fp32 acc) ----------------
// MODE 0: scatter epilogue -> Q(*1/32), K, V  [B,H,T,64] bf16.  MODE 1: fp32 row-major out.
template<int MODE>
__global__ __launch_bounds__(256) void k_gemm(
    const u16* __restrict__ A, const u16* __restrict__ Bt,
    u16* __restrict__ Oq, u16* __restrict__ Ok, u16* __restrict__ Ov,
    float* __restrict__ Of, int K) {
  constexpr int LDK = 40;  // 32 + 8 pad, keeps 16B alignment, breaks pow2 bank stride
  __shared__ __align__(16) u16 As[128 * LDK];
  __shared__ __align__(16) u16 Bs[128 * LDK];
  int mt = blockIdx.x, nt = blockIdx.y;
  int tid = threadIdx.x;
  int wid = tid >> 6, lane = tid & 63;
  int lr = lane & 15, lg = lane >> 4;
  int mw = (wid >> 1) * 64, nw = (wid & 1) * 64;
  int arow = tid >> 1, acol = (tid & 1) * 16;
  const long aBase = (long)(mt * 128 + arow) * K + acol;
  const long bBase = (long)(nt * 128 + arow) * K + acol;
  f32x4 acc[4][4] = {};
  for (int k0 = 0; k0 < K; k0 += 32) {
    short8 av0 = *(const short8*)(A + aBase + k0);
    short8 av1 = *(const short8*)(A + aBase + k0 + 8);
    short8 bv0 = *(const short8*)(Bt + bBase + k0);
    short8 bv1 = *(const short8*)(Bt + bBase + k0 + 8);
    __syncthreads();
    *(short8*)(As + arow * LDK + acol)     = av0;
    *(short8*)(As + arow * LDK + acol + 8) = av1;
    *(short8*)(Bs + arow * LDK + acol)     = bv0;
    *(short8*)(Bs + arow * LDK + acol + 8) = bv1;
    __syncthreads();
    short8 af[4], bf[4];
    #pragma unroll
    for (int i = 0; i < 4; i++)
      af[i] = *(const short8*)(As + (mw + i * 16 + lr) * LDK + lg * 8);
    #pragma unroll
    for (int i = 0; i < 4; i++)
      bf[i] = *(const short8*)(Bs + (nw + i * 16 + lr) * LDK + lg * 8);
    #pragma unroll
    for (int i = 0; i < 4; i++)
      #pragma unroll
      for (int j = 0; j < 4; j++)
        acc[i][j] = __builtin_amdgcn_mfma_f32_16x16x32_bf16(af[i], bf[j], acc[i][j], 0, 0, 0);
  }
  #pragma unroll
  for (int i = 0; i < 4; i++) {
    #pragma unroll
    for (int j = 0; j < 4; j++) {
      int mbase = mt * 128 + mw + i * 16 + lg * 4;      // C/D: row=(lane>>4)*4+r
      int n     = nt * 128 + nw + j * 16 + lr;          //      col=lane&15
      #pragma unroll
      for (int r = 0; r < 4; r++) {
        float val = acc[i][j][r];
        int m = mbase + r;
        if (MODE == 0) {
          int b = m >> 11, t = m & (T_ - 1);
          int h = n / 192, f = n % 192;
          long o = (((long)(b * H_ + h)) * T_ + t) * HS_;
          if (f < 64)       Oq[o + f]       = f2bf(val * 0.03125f);  // fold C^-0.5
          else if (f < 128) Ok[o + f - 64]  = f2bf(val);
          else              Ov[o + f - 128] = f2bf(val);
        } else {
          Of[(long)m * D_ + n] = val;
        }
      }
    }
  }
}

// ---------------- transpose V [bh][T][64] -> Vt [bh][64][T] ----------------
__global__ void k_transpose_v(const u16* __restrict__ V, u16* __restrict__ Vt) {
  __shared__ u16 tile[64][65];
  int bh = blockIdx.z;
  int t0 = blockIdx.x * 64;
  int tx = threadIdx.x & 63, ty = threadIdx.x >> 6;
  const u16* src = V + (long)bh * T_ * HS_;
  u16* dst = Vt + (long)bh * T_ * HS_;
  #pragma unroll
  for (int i = 0; i < 64; i += 4)
    tile[ty + i][tx] = src[(long)(t0 + ty + i) * HS_ + tx];
  __syncthreads();
  #pragma unroll
  for (int i = 0; i < 64; i += 4)
    dst[(long)(ty + i) * T_ + t0 + tx] = tile[tx][ty + i];
}

// ---------------- fused attention (faithful 1e-9 mask => process ALL key tiles) ----------------
__global__ __launch_bounds__(256) void k_attn(
    const u16* __restrict__ Q, const u16* __restrict__ Kc,
    const u16* __restrict__ Vt, u16* __restrict__ Mha) {
  __shared__ __align__(16) u16 Ks[64 * 72];
  __shared__ __align__(16) u16 Vs[64 * 72];
  __shared__ __align__(16) u16 Ps[4][16 * 72];
  int qt = blockIdx.x, bh = blockIdx.y;
  int b = bh >> 4, h = bh & 15;
  int tid = threadIdx.x, wid = tid >> 6, lane = tid & 63;
  int lr = lane & 15, lg = lane >> 4;
  const u16* Qb = Q  + (long)bh * T_ * HS_;
  const u16* Kb = Kc + (long)bh * T_ * HS_;
  const u16* Vb = Vt + (long)bh * T_ * HS_;   // [64][T]
  int qrow = qt * 64 + wid * 16 + lr;         // A-operand: m = lane&15
  short8 qf0 = *(const short8*)(Qb + (long)qrow * HS_ + lg * 8);
  short8 qf1 = *(const short8*)(Qb + (long)qrow * HS_ + 32 + lg * 8);
  f32x4 accO[4] = {};                         // rows lg*4+r, cols fd*16+lr
  float mrun[4], lrun[4];
  #pragma unroll
  for (int r = 0; r < 4; r++) { mrun[r] = -1e30f; lrun[r] = 0.f; }
  int srow = tid >> 2, scol = (tid & 3) * 16;
  for (int j0 = 0; j0 < T_; j0 += 64) {
    __syncthreads();
    *(short8*)(Ks + srow * 72 + scol)     = *(const short8*)(Kb + (long)(j0 + srow) * HS_ + scol);
    *(short8*)(Ks + srow * 72 + scol + 8) = *(const short8*)(Kb + (long)(j0 + srow) * HS_ + scol + 8);
    *(short8*)(Vs + srow * 72 + scol)     = *(const short8*)(Vb + (long)srow * T_ + j0 + scol);
    *(short8*)(Vs + srow * 72 + scol + 8) = *(const short8*)(Vb + (long)srow * T_ + j0 + scol + 8);
    __syncthreads();
    // S = Q K^T  (scale already folded into Q)
    f32x4 s4[4];
    #pragma unroll
    for (int fn = 0; fn < 4; fn++) {
      short8 kb0 = *(const short8*)(Ks + (fn * 16 + lr) * 72 + lg * 8);
      short8 kb1 = *(const short8*)(Ks + (fn * 16 + lr) * 72 + 32 + lg * 8);
      f32x4 z = {};
      z = __builtin_amdgcn_mfma_f32_16x16x32_bf16(qf0, kb0, z, 0, 0, 0);
      z = __builtin_amdgcn_mfma_f32_16x16x32_bf16(qf1, kb1, z, 0, 0, 0);
      s4[fn] = z;
    }
    // online softmax (rows live on 16 lanes sharing lg; reduce over lr via shfl_xor)
    float scl[4];
    float pv[4][4];
    #pragma unroll
    for (int r = 0; r < 4; r++) {
      int trow = qt * 64 + wid * 16 + lg * 4 + r;
      float vals[4];
      #pragma unroll
      for (int fn = 0; fn < 4; fn++) {
        int s = j0 + fn * 16 + lr;
        vals[fn] = (s <= trow) ? s4[fn][r] : 1e-9f;   // faithful masked_fill(1e-9)
      }
      float tmax = fmaxf(fmaxf(vals[0], vals[1]), fmaxf(vals[2], vals[3]));
      #pragma unroll
      for (int sh = 1; sh < 16; sh <<= 1)
        tmax = fmaxf(tmax, __shfl_xor(tmax, sh, 64));
      float mn = fmaxf(mrun[r], tmax);
      scl[r] = __expf(mrun[r] - mn);
      mrun[r] = mn;
      float psum = 0.f;
      #pragma unroll
      for (int fn = 0; fn < 4; fn++) {
        float pe = __expf(vals[fn] - mn);
        pv[fn][r] = pe;
        psum += pe;
      }
      #pragma unroll
      for (int sh = 1; sh < 16; sh <<= 1)
        psum += __shfl_xor(psum, sh, 64);
      lrun[r] = lrun[r] * scl[r] + psum;
    }
    #pragma unroll
    for (int fd = 0; fd < 4; fd++)
      #pragma unroll
      for (int r = 0; r < 4; r++)
        accO[fd][r] *= scl[r];
    // P: D-layout -> A-layout via per-wave LDS bounce
    #pragma unroll
    for (int fn = 0; fn < 4; fn++)
      #pragma unroll
      for (int r = 0; r < 4; r++)
        Ps[wid][(lg * 4 + r) * 72 + fn * 16 + lr] = f2bf(pv[fn][r]);
    short8 pa0 = *(const short8*)(&Ps[wid][lr * 72 + lg * 8]);
    short8 pa1 = *(const short8*)(&Ps[wid][lr * 72 + 32 + lg * 8]);
    #pragma unroll
    for (int fd = 0; fd < 4; fd++) {
      short8 vb0 = *(const short8*)(Vs + (fd * 16 + lr) * 72 + lg * 8);
      short8 vb1 = *(const short8*)(Vs + (fd * 16 + lr) * 72 + 32 + lg * 8);
      accO[fd] = __builtin_amdgcn_mfma_f32_16x16x32_bf16(pa0, vb0, accO[fd], 0, 0, 0);
      accO[fd] = __builtin_amdgcn_mfma_f32_16x16x32_bf16(pa1, vb1, accO[fd], 0, 0, 0);
    }
  }
  #pragma unroll
  for (int fd = 0; fd < 4; fd++) {
    #pragma unroll
    for (int r = 0; r < 4; r++) {
      int trow = qt * 64 + wid * 16 + lg * 4 + r;
      int dcol = fd * 16 + lr;
      float o = accO[fd][r] / lrun[r];
      Mha[((long)(b * T_ + trow)) * D_ + h * HS_ + dcol] = f2bf(o);
    }
  }
}

extern "C" void kernel_launch(void* const* d_in, const int* in_sizes, int n_in,
                              void* d_out, int out_size, void* d_ws, size_t ws_size,
                              hipStream_t stream) {
  const float* x    = (const float*)d_in[0];
  const float* wqkv = (const float*)d_in[1];   // [16][1024][192]
  const float* wout = (const float*)d_in[2];   // [1024][1024]
  float* out = (float*)d_out;

  char* p = (char*)d_ws;
  u16* Xb    = (u16*)p; p += (size_t)M_ * D_ * 2;        // x as bf16 [8192][1024]
  u16* WqkvT = (u16*)p; p += (size_t)NQKV_ * D_ * 2;     // [3072][1024]  (n-major, k-contig)
  u16* WoutT = (u16*)p; p += (size_t)D_ * D_ * 2;        // [1024][1024]  W_out^T
  u16* Qw  = (u16*)p; p += (size_t)B_ * H_ * T_ * HS_ * 2;  // [B,H,T,64], pre-scaled
  u16* Kw  = (u16*)p; p += (size_t)B_ * H_ * T_ * HS_ * 2;
  u16* Vw  = (u16*)p; p += (size_t)B_ * H_ * T_ * HS_ * 2;
  u16* Vtw = (u16*)p; p += (size_t)B_ * H_ * T_ * HS_ * 2;  // [B,H,64,T]
  u16* Mha = (u16*)p; p += (size_t)M_ * D_ * 2;             // [8192][1024]

  k_cvt_x<<<dim3(M_ * D_ / 4 / 256), dim3(256), 0, stream>>>(x, Xb, M_ * D_ / 4);
  k_transpose_cvt<<<dim3(192 / 32, D_ / 32, H_), dim3(32, 8), 0, stream>>>(
      wqkv, WqkvT, D_, 192, (long)D_ * 192, (long)192 * D_);
  k_transpose_cvt<<<dim3(D_ / 32, D_ / 32, 1), dim3(32, 8), 0, stream>>>(
      wout, WoutT, D_, D_, 0, 0);
  k_gemm<0><<<dim3(M_ / 128, NQKV_ / 128), dim3(256), 0, stream>>>(
      Xb, WqkvT, Qw, Kw, Vw, nullptr, D_);
  k_transpose_v<<<dim3(T_ / 64, 1, B_ * H_), dim3(256), 0, stream>>>(Vw, Vtw);
  k_attn<<<dim3(T_ / 64, B_ * H_), dim3(256), 0, stream>>>(Qw, Kw, Vtw, Mha);
  k_gemm<1><<<dim3(M_ / 128, D_ / 128), dim3(256), 0, stream>>>(
      Mha, WoutT, nullptr, nullptr, nullptr, out, D_);
}